// Round 11
// baseline (57.524 us; speedup 1.0000x reference)
//
#include <hip/hip_runtime.h>
#include <hip/hip_bf16.h>

#define B_ 8
#define C_ 96
#define H_ 64
#define W_ 96
#define DD 21
#define NI 3               // i-values per block
#define ISPLIT 7           // 21 / NI
#define LDSTm 37           // Dst row stride (floats): 5 mod 32 -> conflict-light scatter
#define RAWS 49            // prep LDS row stride (uints): conflict-free gather

typedef __attribute__((ext_vector_type(8))) short sh8;
typedef __attribute__((ext_vector_type(4))) float fx4;
typedef __attribute__((ext_vector_type(2))) float f2v;

// Fragment-major bf16 tensors: innermost [lane(64)][e(8)] = 1KB per k-block,
// so a wave's MFMA operand load is base + lane*16B (fully coalesced).
// d1F: [b][y][p][ut(3)][k(3)][lane][8]
// d2F: [b][yp(104)][p][wt(5)][k(3)][lane][8]; border rows yp<20/yp>=84 are
// NEVER WRITTEN OR READ (corr skips them: their outputs are exact zeros).
__device__ __attribute__((aligned(16))) unsigned short g_d1F[B_*H_*2*3*3*512];
__device__ __attribute__((aligned(16))) unsigned short g_d2F[(size_t)B_*104*2*5*3*512];

// Fused prep kernel: grid (128, B).
//  t in [0,64):   d1 row y=t            -> g_d1F
//  t in [64,128): d2 row y=t-64 (interior only, yp=y+20) -> g_d2F
// Inputs are read ONCE -> non-temporal loads keep them out of L2 so the
// fragment tensors (which corr re-reads ~20x) stay resident.
__global__ __launch_bounds__(256) void prep_all(const float* __restrict__ d1,
                                                const float* __restrict__ d2) {
  __shared__ unsigned int raw[C_*RAWS];    // [c][w] packed (p0 | p1<<16)
  const int b = blockIdx.y;
  const int t = blockIdx.x;

  if (t >= 64) {
    const int y = t - 64;
    unsigned short* ob = g_d2F + (size_t)(b*104 + y + 20)*(2*15*512);
    for (int idx = threadIdx.x; idx < C_*48; idx += 256) {
      int c = idx / 48, w = idx % 48;
      const f2v v = __builtin_nontemporal_load(
          (const f2v*)(d2 + (((b*C_ + c)*H_ + y)*W_ + 2*w)));
      __hip_bfloat16 h0 = __float2bfloat16(v[0]), h1 = __float2bfloat16(v[1]);
      raw[c*RAWS + w] = (unsigned)*(unsigned short*)&h0 |
                        ((unsigned)*(unsigned short*)&h1 << 16);
    }
    __syncthreads();
    for (int s = threadIdx.x; s < 2*15*64; s += 256) {
      int lane = s & 63, q = s >> 6;
      int kk = q % 3, wt = (q/3) % 5, p = q / 15;
      int w = wt*16 + (lane & 15) - 10;    // x-pad: stored col = w' - 10
      int cb = kk*32 + (lane >> 4)*8;
      uint4 o; o.x = o.y = o.z = o.w = 0u;
      if (w >= 0 && w < 48) {
        unsigned short tmp[8];
        #pragma unroll
        for (int e = 0; e < 8; ++e) {
          unsigned pk = raw[(cb + e)*RAWS + w];
          tmp[e] = (unsigned short)(p ? (pk >> 16) : pk);
        }
        o = *(const uint4*)tmp;
      }
      *(uint4*)(ob + (size_t)s*8) = o;
    }
  } else {
    const int y = t;
    for (int idx = threadIdx.x; idx < C_*48; idx += 256) {
      int c = idx / 48, w = idx % 48;
      const f2v v = __builtin_nontemporal_load(
          (const f2v*)(d1 + (((b*C_ + c)*H_ + y)*W_ + 2*w)));
      __hip_bfloat16 h0 = __float2bfloat16(v[0]), h1 = __float2bfloat16(v[1]);
      raw[c*RAWS + w] = (unsigned)*(unsigned short*)&h0 |
                        ((unsigned)*(unsigned short*)&h1 << 16);
    }
    __syncthreads();
    unsigned short* ob = g_d1F + (size_t)(b*H_ + y)*(2*9*512);
    for (int s = threadIdx.x; s < 2*9*64; s += 256) {
      int lane = s & 63, q = s >> 6;
      int kk = q % 3, ut = (q/3) % 3, p = q / 9;
      int w = ut*16 + (lane & 15);
      int cb = kk*32 + (lane >> 4)*8;
      unsigned short tmp[8];
      #pragma unroll
      for (int e = 0; e < 8; ++e) {
        unsigned pk = raw[(cb + e)*RAWS + w];
        tmp[e] = (unsigned short)(p ? (pk >> 16) : pk);
      }
      *(uint4*)(ob + (size_t)s*8) = *(const uint4*)tmp;
    }
  }
}

// LDS-only barrier: orders extract(ds_write) -> store(ds_read) across the
// block WITHOUT draining vmcnt -- prefetched global loads stay in flight
// across the barrier (the compiler auto-waits the right vmcnt before the
// MFMAs that consume them). "memory" clobber pins LDS ops on both sides.
#define SYNC_LDS asm volatile("s_waitcnt lgkmcnt(0)\n\ts_barrier" ::: "memory")

// Token-pasting macros over NAMED register arrays (bF0/bF1): every array
// index is compile-time after unroll -> no scratch (rule #20; R5 lesson).
#define LOADB(BF, ROW) do {                                                    \
    const unsigned short* rb_ =                                                \
        g_d2F + (size_t)(((b*104 + (ROW))*2 + p)*5 + mt)*(3*512) + lane*8;     \
    _Pragma("unroll")                                                          \
    for (int n_ = 0; n_ < 3; ++n_)                                             \
      _Pragma("unroll")                                                        \
      for (int k_ = 0; k_ < 3; ++k_)                                           \
        BF[k_*3+n_] = *(const sh8*)(rb_ + (n_*3 + k_)*512);                    \
  } while (0)

// Output stores are NON-TEMPORAL: d_out is write-once/never-read, so
// bypassing L2 allocation keeps d2F resident per-XCD (R10: -2.3us).
// VALID==false (B row entirely in zero padding) -> output plane is exact
// zeros: skip loads/MFMA/LDS, NT-store zeros. Validity is wave-uniform.
// The SYNC_LDS stays unconditional so the Dst ping-pong ordering chain is
// identical in both paths (a wave reaching the barrier has finished its
// ds_reads of the buffer it will later overwrite).
#define COMBO(BF, I, BUF, VALID) do {                                          \
    if (VALID) {                                                               \
      fx4 acc[3] = {fx4{0,0,0,0}, fx4{0,0,0,0}, fx4{0,0,0,0}};                 \
      _Pragma("unroll")                                                        \
      for (int k_ = 0; k_ < 3; ++k_)                                           \
        _Pragma("unroll")                                                      \
        for (int n_ = 0; n_ < 3; ++n_)                                         \
          acc[n_] = __builtin_amdgcn_mfma_f32_16x16x32_bf16(aF[k_],            \
                        BF[k_*3+n_], acc[n_], 0, 0, 0);                        \
      _Pragma("unroll")                                                        \
      for (int n_ = 0; n_ < 3; ++n_)                                           \
        _Pragma("unroll")                                                      \
        for (int r_ = 0; r_ < 4; ++r_) {                                       \
          int j_ = 16*n_ + lr - 4*lg - r_;                                     \
          if (j_ >= 0 && j_ < DD)                                              \
            Dst[BUF][j_*LDSTm + 2*(4*lg + r_) + p] = acc[n_][r_];              \
        }                                                                      \
    }                                                                          \
    SYNC_LDS;                                                                  \
    size_t obase = (size_t)((b*441 + (I)*DD)*H_ + y)*W_ + 2*m0;                \
    if (VALID) {                                                               \
      for (int s_ = threadIdx.x; s_ < DD*32; s_ += 128) {                      \
        int j_ = s_ >> 5, xl_ = s_ & 31;                                       \
        __builtin_nontemporal_store(Dst[BUF][j_*LDSTm + xl_]*scale,            \
                                    out + obase + (size_t)j_*(H_*W_) + xl_);   \
      }                                                                        \
    } else {                                                                   \
      for (int s_ = threadIdx.x; s_ < DD*32; s_ += 128) {                      \
        int j_ = s_ >> 5, xl_ = s_ & 31;                                       \
        __builtin_nontemporal_store(0.0f,                                      \
                                    out + obase + (size_t)j_*(H_*W_) + xl_);   \
      }                                                                        \
    }                                                                          \
  } while (0)

// One block per (b, m-tile, y, i-segment): 128 threads = 2 waves (p=0,1).
// Wave (p): A[u][c]=d1[b,c,y,2u+p], u in [m0,m0+16); B[w'][c]=d2pad[...,2w'+p].
// G=A·B^T band: out[b, i*21+j, y, 2u+p] = G[u, u+j], j in [0,21).
// B rows register-double-buffered: LOADB(next) issues before COMBO(cur), and
// SYNC_LDS lets those loads stay outstanding across the barrier.
__global__ __launch_bounds__(128, 4) void corr_main(const float* __restrict__ s1,
                                                    const float* __restrict__ s2,
                                                    const float* __restrict__ os,
                                                    float* __restrict__ out) {
  __shared__ float Dst[2][DD*LDSTm];
  const int gid = blockIdx.x;
  const int b = gid & 7;                   // XCD affinity
  int t = gid >> 3;
  const int mt = t % 3; t /= 3;
  const int m0 = mt << 4;
  const int y = t & 63;
  const int i0 = (t >> 6) * NI;
  const int p = threadIdx.x >> 6;
  const int lane = threadIdx.x & 63;
  const int lr = lane & 15, lg = lane >> 4;
  const float scale = s1[0]*s2[0] / (96.0f * os[0]);

  sh8 aF[3];
  {
    const unsigned short* aB =
        g_d1F + (size_t)((b*H_ + y)*2 + p)*(9*512) + (size_t)mt*3*512 + lane*8;
    #pragma unroll
    for (int k = 0; k < 3; ++k)
      aF[k] = *(const sh8*)(aB + k*512);
  }

  const int yb = y + 2*i0;                 // B row for i0 (rows step by 2)
  const bool v0 = (yb     >= 20) & (yb     < 84);
  const bool v1 = (yb + 2 >= 20) & (yb + 2 < 84);
  const bool v2 = (yb + 4 >= 20) & (yb + 4 < 84);

  sh8 bF0[9], bF1[9];
  if (v0) LOADB(bF0, yb);
  if (v1) LOADB(bF1, yb + 2);
  COMBO(bF0, i0,     0, v0);
  if (v2) LOADB(bF0, yb + 4);
  COMBO(bF1, i0 + 1, 1, v1);
  COMBO(bF0, i0 + 2, 0, v2);
}

extern "C" void kernel_launch(void* const* d_in, const int* in_sizes, int n_in,
                              void* d_out, int out_size, void* d_ws, size_t ws_size,
                              hipStream_t stream) {
  const float* d1 = (const float*)d_in[0];
  const float* d2 = (const float*)d_in[1];
  const float* s1 = (const float*)d_in[2];
  const float* s2 = (const float*)d_in[3];
  const float* os = (const float*)d_in[5];   // inter_scale (d_in[4]) unused

  prep_all<<<dim3(128, B_), 256, 0, stream>>>(d1, d2);
  corr_main<<<B_*3*H_*ISPLIT, 128, 0, stream>>>(s1, s2, os, (float*)d_out);
}

// Round 12
// 49.359 us; speedup vs baseline: 1.1654x; 1.1654x over previous
//
#include <hip/hip_runtime.h>
#include <hip/hip_bf16.h>

#define B_ 8
#define C_ 96
#define H_ 64
#define W_ 96
#define DD 21
#define LDSTm 37           // Dst row stride (floats): 5 mod 32 -> conflict-light scatter
#define RAWS 49            // prep LDS row stride (uints): conflict-free gather

typedef __attribute__((ext_vector_type(8))) short sh8;
typedef __attribute__((ext_vector_type(4))) float fx4;

// Fragment-major bf16 tensors: innermost [lane(64)][e(8)] = 1KB per k-block,
// so a wave's MFMA operand load is base + lane*16B (fully coalesced).
// d1F: [b][y][p][ut(3)][k(3)][lane][8]
// d2F: [b][yp(104)][p][wt(5)][k(3)][lane][8]   (yp/x padded, borders zero)
__device__ __attribute__((aligned(16))) unsigned short g_d1F[B_*H_*2*3*3*512];
__device__ __attribute__((aligned(16))) unsigned short g_d2F[(size_t)B_*104*2*5*3*512];

// One fused prep kernel: grid (168, B).   [R10 version, verbatim]
//  t in [0,64):    d1 row y=t          -> g_d1F
//  t in [64,168):  d2 padded row yp=t-64 (zero-fill if border) -> g_d2F
__global__ __launch_bounds__(256) void prep_all(const float* __restrict__ d1,
                                                const float* __restrict__ d2) {
  __shared__ unsigned int raw[C_*RAWS];    // [c][w] packed (p0 | p1<<16)
  const int b = blockIdx.y;
  const int t = blockIdx.x;

  if (t >= 64) {
    const int yp = t - 64;
    unsigned short* ob = g_d2F + (size_t)(b*104 + yp)*(2*15*512);
    if (yp < 20 || yp >= 84) {             // border row: pure zero-fill
      uint4 z; z.x = z.y = z.z = z.w = 0u;
      for (int s = threadIdx.x; s < 1920; s += 256)
        *((uint4*)ob + s) = z;
      return;
    }
    const int y = yp - 20;
    for (int idx = threadIdx.x; idx < C_*48; idx += 256) {
      int c = idx / 48, w = idx % 48;
      const float2 v = *(const float2*)(d2 + (((b*C_ + c)*H_ + y)*W_ + 2*w));
      __hip_bfloat16 h0 = __float2bfloat16(v.x), h1 = __float2bfloat16(v.y);
      raw[c*RAWS + w] = (unsigned)*(unsigned short*)&h0 |
                        ((unsigned)*(unsigned short*)&h1 << 16);
    }
    __syncthreads();
    for (int s = threadIdx.x; s < 2*15*64; s += 256) {
      int lane = s & 63, q = s >> 6;
      int kk = q % 3, wt = (q/3) % 5, p = q / 15;
      int w = wt*16 + (lane & 15) - 10;    // x-pad: stored col = w' - 10
      int cb = kk*32 + (lane >> 4)*8;
      uint4 o; o.x = o.y = o.z = o.w = 0u;
      if (w >= 0 && w < 48) {
        unsigned short tmp[8];
        #pragma unroll
        for (int e = 0; e < 8; ++e) {
          unsigned pk = raw[(cb + e)*RAWS + w];
          tmp[e] = (unsigned short)(p ? (pk >> 16) : pk);
        }
        o = *(const uint4*)tmp;
      }
      *(uint4*)(ob + (size_t)s*8) = o;
    }
  } else {
    const int y = t;
    for (int idx = threadIdx.x; idx < C_*48; idx += 256) {
      int c = idx / 48, w = idx % 48;
      const float2 v = *(const float2*)(d1 + (((b*C_ + c)*H_ + y)*W_ + 2*w));
      __hip_bfloat16 h0 = __float2bfloat16(v.x), h1 = __float2bfloat16(v.y);
      raw[c*RAWS + w] = (unsigned)*(unsigned short*)&h0 |
                        ((unsigned)*(unsigned short*)&h1 << 16);
    }
    __syncthreads();
    unsigned short* ob = g_d1F + (size_t)(b*H_ + y)*(2*9*512);
    for (int s = threadIdx.x; s < 2*9*64; s += 256) {
      int lane = s & 63, q = s >> 6;
      int kk = q % 3, ut = (q/3) % 3, p = q / 9;
      int w = ut*16 + (lane & 15);
      int cb = kk*32 + (lane >> 4)*8;
      unsigned short tmp[8];
      #pragma unroll
      for (int e = 0; e < 8; ++e) {
        unsigned pk = raw[(cb + e)*RAWS + w];
        tmp[e] = (unsigned short)(p ? (pk >> 16) : pk);
      }
      *(uint4*)(ob + (size_t)s*8) = *(const uint4*)tmp;
    }
  }
}

// LDS-only barrier: orders extract(ds_write) -> store(ds_read) across the
// block WITHOUT draining vmcnt -- prefetched global loads stay in flight
// across the barrier (the compiler auto-waits the right vmcnt before the
// MFMAs that consume them). "memory" clobber pins LDS ops on both sides.
#define SYNC_LDS asm volatile("s_waitcnt lgkmcnt(0)\n\ts_barrier" ::: "memory")

// Token-pasting macros over NAMED register arrays (bF0/bF1): every array
// index is compile-time after unroll -> no scratch (rule #20; R5 lesson).
#define LOADB(BF, ROW) do {                                                    \
    const unsigned short* rb_ =                                                \
        g_d2F + (size_t)(((b*104 + (ROW))*2 + p)*5 + mt)*(3*512) + lane*8;     \
    _Pragma("unroll")                                                          \
    for (int n_ = 0; n_ < 3; ++n_)                                             \
      _Pragma("unroll")                                                        \
      for (int k_ = 0; k_ < 3; ++k_)                                           \
        BF[k_*3+n_] = *(const sh8*)(rb_ + (n_*3 + k_)*512);                    \
  } while (0)

// Output stores NON-TEMPORAL (R10: -2.3us): d_out is write-once/never-read;
// bypassing L2 allocation keeps d2F resident per-XCD.
#define COMBO(BF, I, BUF) do {                                                 \
    fx4 acc[3] = {fx4{0,0,0,0}, fx4{0,0,0,0}, fx4{0,0,0,0}};                   \
    _Pragma("unroll")                                                          \
    for (int k_ = 0; k_ < 3; ++k_)                                             \
      _Pragma("unroll")                                                        \
      for (int n_ = 0; n_ < 3; ++n_)                                           \
        acc[n_] = __builtin_amdgcn_mfma_f32_16x16x32_bf16(aF[k_], BF[k_*3+n_], \
                                                          acc[n_], 0, 0, 0);   \
    _Pragma("unroll")                                                          \
    for (int n_ = 0; n_ < 3; ++n_)                                             \
      _Pragma("unroll")                                                        \
      for (int r_ = 0; r_ < 4; ++r_) {                                         \
        int j_ = 16*n_ + lr - 4*lg - r_;                                       \
        if (j_ >= 0 && j_ < DD)                                                \
          Dst[BUF][j_*LDSTm + 2*(4*lg + r_) + p] = acc[n_][r_];                \
      }                                                                        \
    SYNC_LDS;                                                                  \
    size_t obase = (size_t)((b*441 + (I)*DD)*H_ + y)*W_ + 2*m0;                \
    for (int s_ = threadIdx.x; s_ < DD*32; s_ += 128) {                        \
      int j_ = s_ >> 5, xl_ = s_ & 31;                                         \
      __builtin_nontemporal_store(Dst[BUF][j_*LDSTm + xl_]*scale,              \
                                  out + obase + (size_t)j_*(H_*W_) + xl_);     \
    }                                                                          \
  } while (0)
// Dst ping-pong race check: extract into BUF happens only after the barrier
// that followed the previous store of the SAME buffer (two combos earlier)
// -- race-free with one LDS barrier per combo.

// One block per (b, m-tile, y) -- NI=21: each block computes its FULL
// i-column. Grid = 1536 blocks = exactly 6 blocks/CU, ALL resident for the
// whole kernel: zero block churn, 12 waves/CU pinned, 21-deep software-
// pipelined loop (B row for combo i+1 always in flight during combo i).
// Wave (p): A[u][c]=d1[b,c,y,2u+p], u in [m0,m0+16); B[w'][c]=d2pad[...,2w'+p].
// G=A·B^T band: out[b, i*21+j, y, 2u+p] = G[u, u+j], j in [0,21).
__global__ __launch_bounds__(128, 4) void corr_main(const float* __restrict__ s1,
                                                    const float* __restrict__ s2,
                                                    const float* __restrict__ os,
                                                    float* __restrict__ out) {
  __shared__ float Dst[2][DD*LDSTm];
  const int gid = blockIdx.x;
  const int b = gid & 7;                   // XCD affinity
  int t = gid >> 3;
  const int mt = t % 3; t /= 3;
  const int m0 = mt << 4;
  const int y = t;                         // [0,64)
  const int p = threadIdx.x >> 6;
  const int lane = threadIdx.x & 63;
  const int lr = lane & 15, lg = lane >> 4;
  const float scale = s1[0]*s2[0] / (96.0f * os[0]);

  sh8 aF[3];
  {
    const unsigned short* aB =
        g_d1F + (size_t)((b*H_ + y)*2 + p)*(9*512) + (size_t)mt*3*512 + lane*8;
    #pragma unroll
    for (int k = 0; k < 3; ++k)
      aF[k] = *(const sh8*)(aB + k*512);
  }

  // B row for combo i is y + 2i (all in [0,104), borders pre-zeroed).
  sh8 bF0[9], bF1[9];
  LOADB(bF0, y);                           // R(0)
  LOADB(bF1, y + 2);                       // R(1)
  #pragma unroll 1
  for (int it = 0; it < 10; ++it) {
    const int i = 2*it;
    COMBO(bF0, i, 0);
    LOADB(bF0, y + 2*(i + 2));             // R(i+2), max R(20) at it=9
    COMBO(bF1, i + 1, 1);
    if (it < 9) LOADB(bF1, y + 2*(i + 3)); // R(i+3), max R(19) at it=8
  }
  COMBO(bF0, 20, 0);
}

extern "C" void kernel_launch(void* const* d_in, const int* in_sizes, int n_in,
                              void* d_out, int out_size, void* d_ws, size_t ws_size,
                              hipStream_t stream) {
  const float* d1 = (const float*)d_in[0];
  const float* d2 = (const float*)d_in[1];
  const float* s1 = (const float*)d_in[2];
  const float* s2 = (const float*)d_in[3];
  const float* os = (const float*)d_in[5];   // inter_scale (d_in[4]) unused

  prep_all<<<dim3(168, B_), 256, 0, stream>>>(d1, d2);
  corr_main<<<B_*3*H_, 128, 0, stream>>>(s1, s2, os, (float*)d_out);
}